// Round 5
// baseline (316.695 us; speedup 1.0000x reference)
//
#include <hip/hip_runtime.h>

// CTC loss forward, T=1024, B=128, C=256, S=128, L=2S+1=257.
// One wave per batch; lane l owns O[2l],O[2l+1] (labels y[2l],y[2l+1]) and
// blanks E[2l],E[2l+1]; E[128] runs as a per-lane sink (real on lane 63).
// FP64 exp-domain states (708-nat range vs ~500-nat state spread), 2^9 bias
// folded into exp2, exact power-of-2 wave renorm every 16 steps.
//
// R3: LLVM sank prefetch loads to uses (VGPR=36, MLP~3) -> ~300 cyc/step HBM
// stall. R4: manual vmcnt(21) raced (spill code breaks vmcnt bookkeeping).
// R5 design: block the loop by 8 steps; issue the next block's 24 loads as
// normal C++ loads, then __builtin_amdgcn_sched_barrier(0) so they cannot be
// sunk below the compute; consume the previous block from registers. The
// compiler inserts the (correct, fine-grained) vmcnt waits at the nxt->cur
// copy, i.e. AFTER a full block of compute -- 24 loads in flight during all
// of each block's math. __launch_bounds__(64,1) = full VGPR budget, no spill.

#define PF 8
#define CTC_C 256
#define EXP_BIAS 9.0f
#define LOG2E 1.4426950408889634f
#define LN2 0.6931471805599453

__global__ __launch_bounds__(64, 1)
void ctc_fwd(const float* __restrict__ lp, const int* __restrict__ y,
             const int* __restrict__ ilen, const int* __restrict__ tlen,
             float* __restrict__ out, int T, int B, int S) {
  const int b = blockIdx.x;
  const int l = threadIdx.x;            // 0..63
  const size_t rowstride = (size_t)B * CTC_C;

  const int len = ilen[b];
  const int tl  = tlen[b];

  const int ya = y[(size_t)b * S + 2 * l];
  const int yb = y[(size_t)b * S + 2 * l + 1];
  const int yprev = __shfl_up(yb, 1);               // y[2l-1]; garbage on lane 0
  const double maskA = (ya != yprev) ? 1.0 : 0.0;   // lane0 ok: its Opm1 is 0
  const double maskB = (yb != ya) ? 1.0 : 0.0;

  // t=0 init: alpha[0]=exp(lp0[blank]) -> E[0]; alpha[1]=exp(lp0[y0]) -> O[0]
  const float* row0 = lp + (size_t)b * CTC_C;
  const int y0 = y[(size_t)b * S];
  double Ea = (l == 0) ? (double)__expf(row0[0])  : 0.0;
  double Oa = (l == 0) ? (double)__expf(row0[y0]) : 0.0;
  double Eb = 0.0, Ob = 0.0, E128 = 0.0;
  double Opm1 = 0.0;
  int e_sum = 0;

  // Gather pointers (per-lane for ya/yb, uniform row walk, clamped at T-1)
  const float* rQ = lp + rowstride + (size_t)b * CTC_C;   // row 1, blank col
  const float* rA = rQ + ya;
  const float* rB = rQ + yb;
  int rrow = 1;                          // row the pointers currently address

  float cA[PF], cB[PF], cQ[PF], nA[PF], nB[PF], nQ[PF];
  // fill cur with rows 1..PF
#pragma unroll
  for (int d = 0; d < PF; ++d) {
    cA[d] = *rA; cB[d] = *rB; cQ[d] = *rQ;
    if (rrow + 1 < T) { rA += rowstride; rB += rowstride; rQ += rowstride; ++rrow; }
  }

  const int nsteps = len - 1;            // steps t = 1..nsteps
  const int nchunks = nsteps / PF;
  int t0 = 1;

  for (int c = 0; c < nchunks; ++c) {
    // ---- issue next block's 24 loads (rows t0+PF .. t0+2PF-1, clamped) ----
#pragma unroll
    for (int d = 0; d < PF; ++d) {
      nA[d] = *rA; nB[d] = *rB; nQ[d] = *rQ;
      if (rrow + 1 < T) { rA += rowstride; rB += rowstride; rQ += rowstride; ++rrow; }
    }
    __builtin_amdgcn_sched_barrier(0);   // loads may not sink below this point

    // ---- 8 steps off cur (loads for the NEXT block are now in flight) ----
#pragma unroll
    for (int d = 0; d < PF; ++d) {
      const float fa = exp2f(fmaf(cA[d], LOG2E, EXP_BIAS));
      const float fb = exp2f(fmaf(cB[d], LOG2E, EXP_BIAS));
      const float fq = exp2f(fmaf(cQ[d], LOG2E, EXP_BIAS));
      const double pa = (double)fa, pb = (double)fb, pq = (double)fq;

      double nOb = fma(maskB, Oa, Ob + Eb) * pb;
      double up = __shfl_up(nOb, 1);     // consumed next step: a step of slack
      double nOa = fma(maskA, Opm1, Oa + Ea) * pa;
      double nEa = (Ea + Opm1) * pq;
      double nEb = (Eb + Oa) * pq;
      E128 = (E128 + Ob) * pq;           // local Ob; real only on lane 63
      Oa = nOa; Ob = nOb; Ea = nEa; Eb = nEb;
      Opm1 = (l == 0) ? 0.0 : up;

      if (d == PF - 1 && (c & 1)) {      // renorm every 16 steps
        double m = fmax(fmax(Oa, Ob), fmax(Ea, Eb));
        m = fmax(m, E128);
#pragma unroll
        for (int off = 32; off > 0; off >>= 1)
          m = fmax(m, __shfl_xor(m, off));
        long long bits = __double_as_longlong(m);
        int eb2 = (int)((bits >> 52) & 0x7ff);
        int e = eb2 - 1022;              // m = f*2^e, f in [0.5,1)
        double s = __longlong_as_double((long long)(2045 - eb2) << 52); // 2^-e
        Oa *= s; Ob *= s; Ea *= s; Eb *= s; E128 *= s; Opm1 *= s;
        e_sum += e;
      }
    }

    // ---- rotate: compiler places the vmcnt waits here, after the compute ----
#pragma unroll
    for (int d = 0; d < PF; ++d) { cA[d] = nA[d]; cB[d] = nB[d]; cQ[d] = nQ[d]; }
    t0 += PF;
  }

  // tail: up to PF-1 steps off cur, wave-uniform predicate
#pragma unroll
  for (int d = 0; d < PF; ++d) {
    const int t = t0 + d;
    if (t <= nsteps) {
      const float fa = exp2f(fmaf(cA[d], LOG2E, EXP_BIAS));
      const float fb = exp2f(fmaf(cB[d], LOG2E, EXP_BIAS));
      const float fq = exp2f(fmaf(cQ[d], LOG2E, EXP_BIAS));
      const double pa = (double)fa, pb = (double)fb, pq = (double)fq;
      double nOb = fma(maskB, Oa, Ob + Eb) * pb;
      double up = __shfl_up(nOb, 1);
      double nOa = fma(maskA, Opm1, Oa + Ea) * pa;
      double nEa = (Ea + Opm1) * pq;
      double nEb = (Eb + Oa) * pq;
      E128 = (E128 + Ob) * pq;
      Oa = nOa; Ob = nOb; Ea = nEa; Eb = nEb;
      Opm1 = (l == 0) ? 0.0 : up;
    }
  }

  // readout: true alpha = stored * 2^(e_sum - 9*nsteps)
  E128 = __shfl(E128, 63);                   // the real E[128]
  double vEa = __shfl(Ea, (tl >> 1) & 63);
  double vEb = __shfl(Eb, (tl >> 1) & 63);
  double vhi = (tl == S) ? E128 : ((tl & 1) ? vEb : vEa);   // alpha[2*tl]
  const int s2 = tl - 1;
  double vOa = __shfl(Oa, (s2 >> 1) & 63);
  double vOb = __shfl(Ob, (s2 >> 1) & 63);
  double vlo = (s2 & 1) ? vOb : vOa;                        // alpha[2*tl-1]

  double sum = vhi + vlo;
  double loss;
  if (sum > 0.0) {
    double ll = log(sum) + (double)(e_sum - 9 * nsteps) * LN2;
    loss = -ll;
  } else {
    loss = 1e30;                             // -inf likelihood
  }
  if (!(loss < 5.0e8)) loss = 0.0;           // zero_infinity (inf/NaN too)
  float contrib = (float)(loss / (double)tl / (double)B);
  if (l == 0) atomicAdd(out, contrib);
}

extern "C" void kernel_launch(void* const* d_in, const int* in_sizes, int n_in,
                              void* d_out, int out_size, void* d_ws, size_t ws_size,
                              hipStream_t stream) {
  const float* lp   = (const float*)d_in[0];
  const int*   yy   = (const int*)d_in[1];
  const int*   ilen = (const int*)d_in[2];
  const int*   tlen = (const int*)d_in[3];
  float* out = (float*)d_out;

  int B = in_sizes[2];
  int S = in_sizes[1] / B;
  int T = in_sizes[0] / (B * CTC_C);

  hipMemsetAsync(out, 0, sizeof(float), stream);
  ctc_fwd<<<B, 64, 0, stream>>>(lp, yy, ilen, tlen, out, T, B, S);
}